// Round 12
// baseline (528.143 us; speedup 1.0000x reference)
//
#include <hip/hip_runtime.h>

#define N_NODES  50000
#define N_EDGES  800000
#define N_GRAPHS 128
#define HD       128                        // hidden dim
#define K2       256                        // GEMM K = [h | msg]
#define CLS      10
#define NB_SCAN  ((N_NODES + 255) / 256)    // 196
#define NPART    8
#define PSIZE    (N_NODES / NPART)          // 6250
#define NBIN     400
#define CHUNK    (N_EDGES / NBIN)           // 2000
#define PCAP     131072
#define AST      264                        // A-tile LDS stride (halfs): 16B-aligned, 2-way bank alias
#define BST      40                         // B-tile LDS stride (halfs)

typedef __attribute__((ext_vector_type(8))) _Float16 f16x8;
typedef __attribute__((ext_vector_type(4))) float f32x4;
typedef __attribute__((ext_vector_type(2))) float f32x2;

union U4H8 { uint4 u; _Float16 h[8]; };
union U2H4 { uint2 u; _Float16 h[4]; };

__device__ inline float h2f(unsigned short s) {
    union { unsigned short u; _Float16 h; } c; c.u = s; return (float)c.h;
}

// ---------------- init: cast features (fp16 + fp8), prep weights, zero deg/gcount/pooled, counts ----------------
__global__ __launch_bounds__(256) void k_init(const float* __restrict__ f,
                                              unsigned short* __restrict__ c0, unsigned char* __restrict__ f8,
                                              const float* __restrict__ Ws0, const float* __restrict__ Wn0,
                                              const float* __restrict__ Ws1, const float* __restrict__ Wn1,
                                              const float* __restrict__ Ws2, const float* __restrict__ Wn2,
                                              unsigned short* __restrict__ wt,
                                              int* __restrict__ zero_region, float* __restrict__ pooled,
                                              const int* __restrict__ gid, float* __restrict__ counts) {
    long long gi = (long long)blockIdx.x * 256 + threadIdx.x;
    if (gi < 800000) {   // features: 8 elems/thread -> fp16 row c0 + fp8 row f8
        int t = (int)gi;
        int row = t >> 4, c8 = (t & 15) * 8;
        const float* p = f + (size_t)row * HD + c8;
        float4 a = *(const float4*)p;
        float4 b = *(const float4*)(p + 4);
        U4H8 v;
        v.h[0] = (_Float16)a.x; v.h[1] = (_Float16)a.y;
        v.h[2] = (_Float16)a.z; v.h[3] = (_Float16)a.w;
        v.h[4] = (_Float16)b.x; v.h[5] = (_Float16)b.y;
        v.h[6] = (_Float16)b.z; v.h[7] = (_Float16)b.w;
        *(uint4*)(c0 + (size_t)row * HD + c8) = v.u;
        int p0 = __builtin_amdgcn_cvt_pk_fp8_f32(a.x, a.y, 0, false);
        p0 = __builtin_amdgcn_cvt_pk_fp8_f32(a.z, a.w, p0, true);
        int p1 = __builtin_amdgcn_cvt_pk_fp8_f32(b.x, b.y, 0, false);
        p1 = __builtin_amdgcn_cvt_pk_fp8_f32(b.z, b.w, p1, true);
        *(uint2*)(f8 + (size_t)row * HD + c8) = make_uint2((unsigned)p0, (unsigned)p1);
        return;
    }
    gi -= 800000;
    if (gi < 3 * HD * K2) {   // weights: transpose+concat -> fp16 [l][n][k]
        int t = (int)gi;
        int l = t / (HD * K2), r = t % (HD * K2);
        int n = r / K2, k = r % K2;
        const float* Ws = (l == 0) ? Ws0 : (l == 1) ? Ws1 : Ws2;
        const float* Wn = (l == 0) ? Wn0 : (l == 1) ? Wn1 : Wn2;
        float w = (k < HD) ? Ws[k * HD + n] : Wn[(k - HD) * HD + n];
        union { unsigned short u; _Float16 h; } c;
        c.h = (_Float16)w;
        wt[t] = c.u;
        return;
    }
    gi -= 3 * HD * K2;
    if (gi < 50056) { zero_region[gi] = 0; return; }   // deg + gcount
    gi -= 50056;
    if (gi < N_GRAPHS * HD) { pooled[gi] = 0.f; return; }
    gi -= (long long)N_GRAPHS * HD;
    if (gi < N_GRAPHS) {   // graph counts via binary search (gid sorted)
        int g = (int)gi;
        int lo = 0, hi = N_NODES;
        while (lo < hi) { int mid = (lo + hi) >> 1; if (gid[mid] < g) lo = mid + 1; else hi = mid; }
        int start = lo;
        lo = 0; hi = N_NODES;
        while (lo < hi) { int mid = (lo + hi) >> 1; if (gid[mid] <= g) lo = mid + 1; else hi = mid; }
        counts[g] = (float)(lo - start);
    }
}
#define INIT_THREADS (800000 + 3 * HD * K2 + 50056 + N_GRAPHS * HD + N_GRAPHS)

// ---------------- bin edges by dst partition (wave-aggregated LDS atomics) ----------------
__global__ __launch_bounds__(256) void k_bin(const int* __restrict__ src, const int* __restrict__ dst,
                                             int2* __restrict__ stag, int* __restrict__ gcount) {
    __shared__ int lcount[NPART];
    __shared__ int lbase[NPART];
    const int tid = threadIdx.x;
    const int lane = tid & 63;
    const int lo = blockIdx.x * CHUNK;
    if (tid < NPART) lcount[tid] = 0;
    __syncthreads();
    for (int i = lo + tid; i < lo + CHUNK; i += 256) {
        int p = dst[i] / PSIZE;
#pragma unroll
        for (int q = 0; q < NPART; ++q) {
            unsigned long long m = __ballot(p == q);
            if (p == q) {
                int leader = __ffsll((long long)m) - 1;
                if (lane == leader) atomicAdd(&lcount[q], (int)__popcll(m));
            }
        }
    }
    __syncthreads();
    if (tid < NPART) {
        lbase[tid] = atomicAdd(&gcount[tid], lcount[tid]);
        lcount[tid] = 0;   // reuse as cursor
    }
    __syncthreads();
    for (int i = lo + tid; i < lo + CHUNK; i += 256) {
        int d = dst[i];
        int p = d / PSIZE;
        int slot = 0;
#pragma unroll
        for (int q = 0; q < NPART; ++q) {
            unsigned long long m = __ballot(p == q);
            if (p == q) {
                int leader = __ffsll((long long)m) - 1;
                int rank = (int)__popcll(m & ((1ull << lane) - 1ull));
                int base;
                if (lane == leader) base = atomicAdd(&lcount[q], (int)__popcll(m));
                base = __shfl(base, leader);
                slot = base + rank;
            }
        }
        stag[(size_t)p * PCAP + lbase[p] + slot] = make_int2(src[i], d);
    }
}

// ---------------- degree count from staged pairs (XCD-local atomics) ----------------
__global__ __launch_bounds__(256) void k_deg2(const int2* __restrict__ stag, const int* __restrict__ gcount,
                                              int* __restrict__ deg) {
    const int part = blockIdx.x & (NPART - 1);
    const int blk = blockIdx.x >> 3;
    const int n = gcount[part];
    const int2* s = stag + (size_t)part * PCAP;
    for (int i = blk * 256 + threadIdx.x; i < n; i += 64 * 256)
        atomicAdd(&deg[s[i].y], 1);
}

// ---------------- CSR fill from staged pairs (XCD-local) ----------------
__global__ __launch_bounds__(256) void k_fill2(const int2* __restrict__ stag, const int* __restrict__ gcount,
                                               int* __restrict__ cursor, int* __restrict__ eidx) {
    const int part = blockIdx.x & (NPART - 1);
    const int blk = blockIdx.x >> 3;
    const int n = gcount[part];
    const int2* s = stag + (size_t)part * PCAP;
    for (int i = blk * 256 + threadIdx.x; i < n; i += 64 * 256) {
        int2 e = s[i];
        int pos = atomicAdd(&cursor[e.y], 1);
        eidx[pos] = e.x;
    }
}

// ---------------- scan phase 1: per-block local exclusive scan ----------------
__global__ __launch_bounds__(256) void k_scan_part(const int* __restrict__ deg,
                                                   int* __restrict__ rowptr, int* __restrict__ bsum) {
    __shared__ int s[256];
    const int tid = threadIdx.x;
    const int i = blockIdx.x * 256 + tid;
    int v = (i < N_NODES) ? deg[i] : 0;
    s[tid] = v;
    __syncthreads();
    for (int off = 1; off < 256; off <<= 1) {
        int add = (tid >= off) ? s[tid - off] : 0;
        __syncthreads();
        s[tid] += add;
        __syncthreads();
    }
    if (i < N_NODES) rowptr[i] = s[tid] - v;
    if (tid == 255) bsum[blockIdx.x] = s[255];
}

// ---------------- scan phase 2: redundant top-scan per block + add offsets ----------------
__global__ __launch_bounds__(256) void k_scan_add(int* __restrict__ rowptr, const int* __restrict__ bsum,
                                                  int* __restrict__ cursor) {
    __shared__ int s[256];
    __shared__ int off_sh;
    const int tid = threadIdx.x;
    int v = (tid < NB_SCAN) ? bsum[tid] : 0;
    s[tid] = v;
    __syncthreads();
    for (int off = 1; off < 256; off <<= 1) {
        int add = (tid >= off) ? s[tid - off] : 0;
        __syncthreads();
        s[tid] += add;
        __syncthreads();
    }
    if (tid == blockIdx.x) off_sh = s[tid] - v;
    __syncthreads();
    const int i = blockIdx.x * 256 + tid;
    if (i < N_NODES) {
        int r = rowptr[i] + off_sh;
        rowptr[i] = r;
        cursor[i] = r;
    }
    if (blockIdx.x == 0 && tid == 0) rowptr[N_NODES] = N_EDGES;
}

// ---------------- fused SAGE layer: in-LDS gather (fp8) + fp16 MFMA K=256 GEMM ----------------
// A-tile = [self h fp16 | gathered neighbor-mean] built in LDS; msg never hits global.
__global__ __launch_bounds__(256) void k_sage_f(const unsigned short* __restrict__ hin,  // [m][128] fp16
                                                const unsigned char* __restrict__ h8,    // [m][128] fp8
                                                const int* __restrict__ rowptr,
                                                const int* __restrict__ eidx,
                                                const unsigned short* __restrict__ wt,   // [n][256] fp16
                                                const float* __restrict__ bias,
                                                unsigned short* __restrict__ hout,       // [m][128] fp16
                                                unsigned char* __restrict__ hout8) {     // [m][128] fp8
    __shared__ _Float16 As[128 * AST];   // 67.6 KB: [row][k 0..255]
    __shared__ _Float16 Bw[128 * BST];   // 10 KB per-chunk weight tile
    const int tid = threadIdx.x;
    const int wv = tid >> 6, lane = tid & 63;
    const int m0 = blockIdx.x * 128;
    const int epar = lane >> 4;          // 4 edge slots
    const int d0 = (lane & 15) * 8;      // 8 elems per lane

    // phase 1: stage self h-part (cols 0..127)
#pragma unroll
    for (int p = 0; p < 8; ++p) {
        int linear = p * 2048 + tid * 8;
        int row = linear >> 7, col = linear & 127;
        int gm = m0 + row;
        uint4 v = make_uint4(0u, 0u, 0u, 0u);
        if (gm < N_NODES) v = *(const uint4*)(hin + (size_t)gm * HD + col);
        *(uint4*)&As[row * AST + col] = v;
    }
    // phase 2: gather neighbor means into cols 128..255 (wave wv owns rows wv*32..+31)
    for (int t = 0; t < 32; ++t) {
        const int row = wv * 32 + t;
        const int node = m0 + row;
        int beg = 0, end = 0;
        if (node < N_NODES) { beg = rowptr[node]; end = rowptr[node + 1]; }
        float acc[8] = {0.f, 0.f, 0.f, 0.f, 0.f, 0.f, 0.f, 0.f};
        int j = beg + epar;
        for (; j + 4 < end; j += 8) {   // 8 edges in flight per wave
            int s0 = eidx[j], s1 = eidx[j + 4];
            uint2 v0 = *(const uint2*)(h8 + (size_t)s0 * HD + d0);
            uint2 v1 = *(const uint2*)(h8 + (size_t)s1 * HD + d0);
            f32x2 e;
            e = __builtin_amdgcn_cvt_pk_f32_fp8(v0.x, false); acc[0] += e[0]; acc[1] += e[1];
            e = __builtin_amdgcn_cvt_pk_f32_fp8(v0.x, true);  acc[2] += e[0]; acc[3] += e[1];
            e = __builtin_amdgcn_cvt_pk_f32_fp8(v0.y, false); acc[4] += e[0]; acc[5] += e[1];
            e = __builtin_amdgcn_cvt_pk_f32_fp8(v0.y, true);  acc[6] += e[0]; acc[7] += e[1];
            e = __builtin_amdgcn_cvt_pk_f32_fp8(v1.x, false); acc[0] += e[0]; acc[1] += e[1];
            e = __builtin_amdgcn_cvt_pk_f32_fp8(v1.x, true);  acc[2] += e[0]; acc[3] += e[1];
            e = __builtin_amdgcn_cvt_pk_f32_fp8(v1.y, false); acc[4] += e[0]; acc[5] += e[1];
            e = __builtin_amdgcn_cvt_pk_f32_fp8(v1.y, true);  acc[6] += e[0]; acc[7] += e[1];
        }
        if (j < end) {
            uint2 v0 = *(const uint2*)(h8 + (size_t)eidx[j] * HD + d0);
            f32x2 e;
            e = __builtin_amdgcn_cvt_pk_f32_fp8(v0.x, false); acc[0] += e[0]; acc[1] += e[1];
            e = __builtin_amdgcn_cvt_pk_f32_fp8(v0.x, true);  acc[2] += e[0]; acc[3] += e[1];
            e = __builtin_amdgcn_cvt_pk_f32_fp8(v0.y, false); acc[4] += e[0]; acc[5] += e[1];
            e = __builtin_amdgcn_cvt_pk_f32_fp8(v0.y, true);  acc[6] += e[0]; acc[7] += e[1];
        }
#pragma unroll
        for (int i = 0; i < 8; ++i) {
            acc[i] += __shfl_xor(acc[i], 16);
            acc[i] += __shfl_xor(acc[i], 32);
        }
        if (epar == 0) {
            float inv = (end > beg) ? 1.0f / (float)(end - beg) : 0.f;
            U4H8 o;
#pragma unroll
            for (int i = 0; i < 8; ++i) o.h[i] = (_Float16)(acc[i] * inv);
            *(uint4*)&As[row * AST + HD + d0] = o.u;
        }
    }
    __syncthreads();

    // phase 3: K=256 MFMA GEMM, A from LDS, W chunked
    const int m_off = (wv >> 1) * 64, n_off = (wv & 1) * 64;
    const int l15 = lane & 15, q = lane >> 4;
    f32x4 acc[4][4];
#pragma unroll
    for (int a = 0; a < 4; ++a)
#pragma unroll
        for (int b = 0; b < 4; ++b) acc[a][b] = (f32x4){0.f, 0.f, 0.f, 0.f};

#pragma unroll 1
    for (int kt = 0; kt < 8; ++kt) {
        const int k0 = kt * 32;
#pragma unroll
        for (int i = 0; i < 2; ++i) {
            int idx = tid + i * 256;
            int row = idx >> 2, kq = (idx & 3) * 8;
            *(uint4*)&Bw[row * BST + kq] = *(const uint4*)(wt + (size_t)row * K2 + k0 + kq);
        }
        __syncthreads();
        f16x8 hf[4], wf[4];
#pragma unroll
        for (int mt = 0; mt < 4; ++mt)
            hf[mt] = *(const f16x8*)&As[(m_off + mt * 16 + l15) * AST + k0 + q * 8];
#pragma unroll
        for (int nt = 0; nt < 4; ++nt)
            wf[nt] = *(const f16x8*)&Bw[(n_off + nt * 16 + l15) * BST + q * 8];
#pragma unroll
        for (int mt = 0; mt < 4; ++mt)
#pragma unroll
            for (int nt = 0; nt < 4; ++nt)
                acc[mt][nt] = __builtin_amdgcn_mfma_f32_16x16x32_f16(wf[nt], hf[mt], acc[mt][nt], 0, 0, 0);
        __syncthreads();
    }
    // epilogue: bias + relu; fp16 out + fp8 shadow
#pragma unroll
    for (int nt = 0; nt < 4; ++nt) {
        int n = n_off + nt * 16 + q * 4;
        float4 bv = *(const float4*)(bias + n);
#pragma unroll
        for (int mt = 0; mt < 4; ++mt) {
            int m = m0 + m_off + mt * 16 + l15;
            if (m < N_NODES) {
                f32x4 a = acc[mt][nt];
                float r0 = fmaxf(a[0] + bv.x, 0.f);
                float r1 = fmaxf(a[1] + bv.y, 0.f);
                float r2 = fmaxf(a[2] + bv.z, 0.f);
                float r3 = fmaxf(a[3] + bv.w, 0.f);
                U2H4 v;
                v.h[0] = (_Float16)r0; v.h[1] = (_Float16)r1;
                v.h[2] = (_Float16)r2; v.h[3] = (_Float16)r3;
                *(uint2*)(hout + (size_t)m * HD + n) = v.u;
                int p = __builtin_amdgcn_cvt_pk_fp8_f32(r0, r1, 0, false);
                p = __builtin_amdgcn_cvt_pk_fp8_f32(r2, r3, p, true);
                *(unsigned int*)(hout8 + (size_t)m * HD + n) = (unsigned)p;
            }
        }
    }
}

// ---------------- graph mean-pool (fp16 h, sorted gids) ----------------
__global__ __launch_bounds__(256) void k_pool(const unsigned short* __restrict__ h,
                                              const int* __restrict__ gid,
                                              float* __restrict__ pooled) {
    int d = threadIdx.x & 127;
    int half = threadIdx.x >> 7;
    int n0 = blockIdx.x * 128;
    float acc = 0.f;
    int cur = -1;
    for (int i = half; i < 128; i += 2) {
        int n = n0 + i;
        if (n >= N_NODES) break;
        int g = gid[n];
        if (g != cur) {
            if (cur >= 0) atomicAdd(&pooled[(size_t)cur * HD + d], acc);
            acc = 0.f;
            cur = g;
        }
        acc += h2f(h[(size_t)n * HD + d]);
    }
    if (cur >= 0) atomicAdd(&pooled[(size_t)cur * HD + d], acc);
}

// ---------------- classifier (fp32) ----------------
__global__ __launch_bounds__(256) void k_final(const float* __restrict__ pooled,
                                               const float* __restrict__ counts,
                                               const float* __restrict__ Wf,
                                               const float* __restrict__ bf,
                                               float* __restrict__ out) {
    int t = blockIdx.x * 256 + threadIdx.x;
    if (t >= N_GRAPHS * CLS) return;
    int g = t / CLS, c = t % CLS;
    float inv = 1.0f / fmaxf(counts[g], 1.0f);
    float s = 0.f;
    for (int k = 0; k < HD; ++k) s += pooled[(size_t)g * HD + k] * Wf[k * CLS + c];
    out[t] = s * inv + bf[c];
}

extern "C" void kernel_launch(void* const* d_in, const int* in_sizes, int n_in,
                              void* d_out, int out_size, void* d_ws, size_t ws_size,
                              hipStream_t stream) {
    const float* features = (const float*)d_in[0];
    const int*   esrc     = (const int*)d_in[1];
    const int*   edst     = (const int*)d_in[2];
    const int*   gids     = (const int*)d_in[3];
    const float* bs[3]  = {(const float*)d_in[6], (const float*)d_in[9], (const float*)d_in[12]};
    const float* Wf = (const float*)d_in[13];
    const float* bfv = (const float*)d_in[14];
    float* out = (float*)d_out;

    // ---- workspace layout ----
    int* deg_i  = (int*)d_ws;            // 50000 + gcount (zeroed as 50056 block)
    int* gcount = deg_i + 50000;         // 8
    int* rowptr = deg_i + 50056;         // 50064
    int* cursor = rowptr + 50064;        // 50048
    int* bsum   = cursor + 50048;        // 256
    int* eidx   = bsum + 256;            // 800000
    int2* stag  = (int2*)(eidx + 800000);        // 8*131072 int2 = 8 MB
    float* pooled = (float*)(stag + (size_t)NPART * PCAP);   // 16384
    float* counts = pooled + N_GRAPHS * HD;      // 128
    unsigned short* C0 = (unsigned short*)(counts + 128);    // 50000*128 fp16 x3
    unsigned short* C1 = C0 + (size_t)N_NODES * HD;
    unsigned short* C2 = C1 + (size_t)N_NODES * HD;
    unsigned short* Wt = C2 + (size_t)N_NODES * HD;          // 3*128*256 fp16
    unsigned char* F0 = (unsigned char*)(Wt + 3 * HD * K2);  // 50000*128 fp8 x3
    unsigned char* F1 = F0 + (size_t)N_NODES * HD;
    unsigned char* F2 = F1 + (size_t)N_NODES * HD;
    // total ~70 MB

    // init: casts + weight prep + zeroing + graph counts (one dispatch)
    k_init<<<(INIT_THREADS + 255) / 256, 256, 0, stream>>>(
        features, C0, F0,
        (const float*)d_in[4], (const float*)d_in[5],
        (const float*)d_in[7], (const float*)d_in[8],
        (const float*)d_in[10], (const float*)d_in[11],
        Wt, deg_i, pooled, gids, counts);

    // CSR build: bin -> deg (XCD-local) -> scan x2 -> fill
    k_bin<<<NBIN, 256, 0, stream>>>(esrc, edst, stag, gcount);
    k_deg2<<<NPART * 64, 256, 0, stream>>>(stag, gcount, deg_i);
    k_scan_part<<<NB_SCAN, 256, 0, stream>>>(deg_i, rowptr, bsum);
    k_scan_add<<<NB_SCAN, 256, 0, stream>>>(rowptr, bsum, cursor);
    k_fill2<<<NPART * 64, 256, 0, stream>>>(stag, gcount, cursor, eidx);

    unsigned short* C[4] = {C0, C1, C2, C0};
    unsigned char* F[4] = {F0, F1, F2, F0};
    for (int l = 0; l < 3; ++l) {
        k_sage_f<<<(N_NODES + 127) / 128, 256, 0, stream>>>(
            C[l], F[l], rowptr, eidx, Wt + (size_t)l * HD * K2, bs[l], C[l + 1], F[l + 1]);
    }

    k_pool<<<(N_NODES + 127) / 128, 256, 0, stream>>>(C0, gids, pooled);
    k_final<<<(N_GRAPHS * CLS + 255) / 256, 256, 0, stream>>>(pooled, counts, Wf, bfv, out);
}

// Round 13
// 417.774 us; speedup vs baseline: 1.2642x; 1.2642x over previous
//
#include <hip/hip_runtime.h>

#define N_NODES  50000
#define N_EDGES  800000
#define N_GRAPHS 128
#define HD       128
#define K2       256
#define CLS      10
#define NB_SCAN  ((N_NODES + 255) / 256)    // 196
#define NPART    8
#define PSIZE    (N_NODES / NPART)          // 6250
#define NBIN     400
#define CHUNK    (N_EDGES / NBIN)           // 2000
#define PCAP     131072
#define NB_POOL  ((N_NODES + 127) / 128)    // 391

typedef __attribute__((ext_vector_type(8))) _Float16 f16x8;
typedef __attribute__((ext_vector_type(4))) float f32x4;
typedef __attribute__((ext_vector_type(2))) float f32x2;

union U4H8 { uint4 u; _Float16 h[8]; };
union U2H4 { uint2 u; _Float16 h[4]; };

__device__ inline float h2f(unsigned short s) {
    union { unsigned short u; _Float16 h; } c; c.u = s; return (float)c.h;
}

// ---------------- init: cast features (fp16 + fp8), prep weights, zero deg/gcount/done/pooled, counts ----------------
__global__ __launch_bounds__(256) void k_init(const float* __restrict__ f,
                                              unsigned short* __restrict__ c0, unsigned char* __restrict__ f8,
                                              const float* __restrict__ Ws0, const float* __restrict__ Wn0,
                                              const float* __restrict__ Ws1, const float* __restrict__ Wn1,
                                              const float* __restrict__ Ws2, const float* __restrict__ Wn2,
                                              unsigned short* __restrict__ wt,
                                              int* __restrict__ zero_region, float* __restrict__ pooled,
                                              const int* __restrict__ gid, float* __restrict__ counts) {
    long long gi = (long long)blockIdx.x * 256 + threadIdx.x;
    if (gi < 800000) {   // features: 8 elems/thread -> fp16 row (K2-strided h-part) + fp8 row
        int t = (int)gi;
        int row = t >> 4, c8 = (t & 15) * 8;
        const float* p = f + (size_t)row * HD + c8;
        float4 a = *(const float4*)p;
        float4 b = *(const float4*)(p + 4);
        U4H8 v;
        v.h[0] = (_Float16)a.x; v.h[1] = (_Float16)a.y;
        v.h[2] = (_Float16)a.z; v.h[3] = (_Float16)a.w;
        v.h[4] = (_Float16)b.x; v.h[5] = (_Float16)b.y;
        v.h[6] = (_Float16)b.z; v.h[7] = (_Float16)b.w;
        *(uint4*)(c0 + (size_t)row * K2 + c8) = v.u;
        int p0 = __builtin_amdgcn_cvt_pk_fp8_f32(a.x, a.y, 0, false);
        p0 = __builtin_amdgcn_cvt_pk_fp8_f32(a.z, a.w, p0, true);
        int p1 = __builtin_amdgcn_cvt_pk_fp8_f32(b.x, b.y, 0, false);
        p1 = __builtin_amdgcn_cvt_pk_fp8_f32(b.z, b.w, p1, true);
        *(uint2*)(f8 + (size_t)row * HD + c8) = make_uint2((unsigned)p0, (unsigned)p1);
        return;
    }
    gi -= 800000;
    if (gi < 3 * HD * K2) {   // weights: transpose+concat -> fp16 [l][n][k]
        int t = (int)gi;
        int l = t / (HD * K2), r = t % (HD * K2);
        int n = r / K2, k = r % K2;
        const float* Ws = (l == 0) ? Ws0 : (l == 1) ? Ws1 : Ws2;
        const float* Wn = (l == 0) ? Wn0 : (l == 1) ? Wn1 : Wn2;
        float w = (k < HD) ? Ws[k * HD + n] : Wn[(k - HD) * HD + n];
        union { unsigned short u; _Float16 h; } c;
        c.h = (_Float16)w;
        wt[t] = c.u;
        return;
    }
    gi -= 3 * HD * K2;
    if (gi < 50064) { zero_region[gi] = 0; return; }   // deg + gcount + done
    gi -= 50064;
    if (gi < N_GRAPHS * HD) { pooled[gi] = 0.f; return; }
    gi -= (long long)N_GRAPHS * HD;
    if (gi < N_GRAPHS) {   // graph counts via binary search (gid sorted)
        int g = (int)gi;
        int lo = 0, hi = N_NODES;
        while (lo < hi) { int mid = (lo + hi) >> 1; if (gid[mid] < g) lo = mid + 1; else hi = mid; }
        int start = lo;
        lo = 0; hi = N_NODES;
        while (lo < hi) { int mid = (lo + hi) >> 1; if (gid[mid] <= g) lo = mid + 1; else hi = mid; }
        counts[g] = (float)(lo - start);
    }
}
#define INIT_THREADS (800000 + 3 * HD * K2 + 50064 + N_GRAPHS * HD + N_GRAPHS)

// ---------------- bin edges by dst partition (wave-aggregated LDS atomics) ----------------
__global__ __launch_bounds__(256) void k_bin(const int* __restrict__ src, const int* __restrict__ dst,
                                             int2* __restrict__ stag, int* __restrict__ gcount) {
    __shared__ int lcount[NPART];
    __shared__ int lbase[NPART];
    const int tid = threadIdx.x;
    const int lane = tid & 63;
    const int lo = blockIdx.x * CHUNK;
    if (tid < NPART) lcount[tid] = 0;
    __syncthreads();
    for (int i = lo + tid; i < lo + CHUNK; i += 256) {
        int p = dst[i] / PSIZE;
#pragma unroll
        for (int q = 0; q < NPART; ++q) {
            unsigned long long m = __ballot(p == q);
            if (p == q) {
                int leader = __ffsll((long long)m) - 1;
                if (lane == leader) atomicAdd(&lcount[q], (int)__popcll(m));
            }
        }
    }
    __syncthreads();
    if (tid < NPART) {
        lbase[tid] = atomicAdd(&gcount[tid], lcount[tid]);
        lcount[tid] = 0;   // reuse as cursor
    }
    __syncthreads();
    for (int i = lo + tid; i < lo + CHUNK; i += 256) {
        int d = dst[i];
        int p = d / PSIZE;
        int slot = 0;
#pragma unroll
        for (int q = 0; q < NPART; ++q) {
            unsigned long long m = __ballot(p == q);
            if (p == q) {
                int leader = __ffsll((long long)m) - 1;
                int rank = (int)__popcll(m & ((1ull << lane) - 1ull));
                int base;
                if (lane == leader) base = atomicAdd(&lcount[q], (int)__popcll(m));
                base = __shfl(base, leader);
                slot = base + rank;
            }
        }
        stag[(size_t)p * PCAP + lbase[p] + slot] = make_int2(src[i], d);
    }
}

// ---------------- degree count from staged pairs (XCD-local atomics) ----------------
__global__ __launch_bounds__(256) void k_deg2(const int2* __restrict__ stag, const int* __restrict__ gcount,
                                              int* __restrict__ deg) {
    const int part = blockIdx.x & (NPART - 1);
    const int blk = blockIdx.x >> 3;
    const int n = gcount[part];
    const int2* s = stag + (size_t)part * PCAP;
    for (int i = blk * 256 + threadIdx.x; i < n; i += 64 * 256)
        atomicAdd(&deg[s[i].y], 1);
}

// ---------------- CSR fill from staged pairs (XCD-local) ----------------
__global__ __launch_bounds__(256) void k_fill2(const int2* __restrict__ stag, const int* __restrict__ gcount,
                                               int* __restrict__ cursor, int* __restrict__ eidx) {
    const int part = blockIdx.x & (NPART - 1);
    const int blk = blockIdx.x >> 3;
    const int n = gcount[part];
    const int2* s = stag + (size_t)part * PCAP;
    for (int i = blk * 256 + threadIdx.x; i < n; i += 64 * 256) {
        int2 e = s[i];
        int pos = atomicAdd(&cursor[e.y], 1);
        eidx[pos] = e.x;
    }
}

// ---------------- scan phase 1: per-block local exclusive scan ----------------
__global__ __launch_bounds__(256) void k_scan_part(const int* __restrict__ deg,
                                                   int* __restrict__ rowptr, int* __restrict__ bsum) {
    __shared__ int s[256];
    const int tid = threadIdx.x;
    const int i = blockIdx.x * 256 + tid;
    int v = (i < N_NODES) ? deg[i] : 0;
    s[tid] = v;
    __syncthreads();
    for (int off = 1; off < 256; off <<= 1) {
        int add = (tid >= off) ? s[tid - off] : 0;
        __syncthreads();
        s[tid] += add;
        __syncthreads();
    }
    if (i < N_NODES) rowptr[i] = s[tid] - v;
    if (tid == 255) bsum[blockIdx.x] = s[255];
}

// ---------------- scan phase 2: redundant top-scan per block + add offsets ----------------
__global__ __launch_bounds__(256) void k_scan_add(int* __restrict__ rowptr, const int* __restrict__ bsum,
                                                  int* __restrict__ cursor) {
    __shared__ int s[256];
    __shared__ int off_sh;
    const int tid = threadIdx.x;
    int v = (tid < NB_SCAN) ? bsum[tid] : 0;
    s[tid] = v;
    __syncthreads();
    for (int off = 1; off < 256; off <<= 1) {
        int add = (tid >= off) ? s[tid - off] : 0;
        __syncthreads();
        s[tid] += add;
        __syncthreads();
    }
    if (tid == blockIdx.x) off_sh = s[tid] - v;
    __syncthreads();
    const int i = blockIdx.x * 256 + tid;
    if (i < N_NODES) {
        int r = rowptr[i] + off_sh;
        rowptr[i] = r;
        cursor[i] = r;
    }
    if (blockIdx.x == 0 && tid == 0) rowptr[N_NODES] = N_EDGES;
}

// ---------------- gather: one wave per node, fp8 rows, fp32 accum, 16 edges in flight ----------------
__global__ __launch_bounds__(256) void k_gather(const unsigned char* __restrict__ h8,
                                                const int* __restrict__ rowptr,
                                                const int* __restrict__ eidx,
                                                unsigned short* __restrict__ msg) {
    const int node = (blockIdx.x * 256 + threadIdx.x) >> 6;
    const int lane = threadIdx.x & 63;
    if (node >= N_NODES) return;
    const int epar = lane >> 4;        // 4 edge slots
    const int d0 = (lane & 15) * 8;    // 8 fp8 per lane = 8 B
    const int beg = rowptr[node], end = rowptr[node + 1];
    float acc[8] = {0.f, 0.f, 0.f, 0.f, 0.f, 0.f, 0.f, 0.f};
    int j = beg + epar;
    for (; j + 12 < end; j += 16) {    // 16 edges in flight per wave
        int s0 = eidx[j], s1 = eidx[j + 4], s2 = eidx[j + 8], s3 = eidx[j + 12];
        uint2 v0 = *(const uint2*)(h8 + (size_t)s0 * HD + d0);
        uint2 v1 = *(const uint2*)(h8 + (size_t)s1 * HD + d0);
        uint2 v2 = *(const uint2*)(h8 + (size_t)s2 * HD + d0);
        uint2 v3 = *(const uint2*)(h8 + (size_t)s3 * HD + d0);
        f32x2 e;
        e = __builtin_amdgcn_cvt_pk_f32_fp8(v0.x, false); acc[0] += e[0]; acc[1] += e[1];
        e = __builtin_amdgcn_cvt_pk_f32_fp8(v0.x, true);  acc[2] += e[0]; acc[3] += e[1];
        e = __builtin_amdgcn_cvt_pk_f32_fp8(v0.y, false); acc[4] += e[0]; acc[5] += e[1];
        e = __builtin_amdgcn_cvt_pk_f32_fp8(v0.y, true);  acc[6] += e[0]; acc[7] += e[1];
        e = __builtin_amdgcn_cvt_pk_f32_fp8(v1.x, false); acc[0] += e[0]; acc[1] += e[1];
        e = __builtin_amdgcn_cvt_pk_f32_fp8(v1.x, true);  acc[2] += e[0]; acc[3] += e[1];
        e = __builtin_amdgcn_cvt_pk_f32_fp8(v1.y, false); acc[4] += e[0]; acc[5] += e[1];
        e = __builtin_amdgcn_cvt_pk_f32_fp8(v1.y, true);  acc[6] += e[0]; acc[7] += e[1];
        e = __builtin_amdgcn_cvt_pk_f32_fp8(v2.x, false); acc[0] += e[0]; acc[1] += e[1];
        e = __builtin_amdgcn_cvt_pk_f32_fp8(v2.x, true);  acc[2] += e[0]; acc[3] += e[1];
        e = __builtin_amdgcn_cvt_pk_f32_fp8(v2.y, false); acc[4] += e[0]; acc[5] += e[1];
        e = __builtin_amdgcn_cvt_pk_f32_fp8(v2.y, true);  acc[6] += e[0]; acc[7] += e[1];
        e = __builtin_amdgcn_cvt_pk_f32_fp8(v3.x, false); acc[0] += e[0]; acc[1] += e[1];
        e = __builtin_amdgcn_cvt_pk_f32_fp8(v3.x, true);  acc[2] += e[0]; acc[3] += e[1];
        e = __builtin_amdgcn_cvt_pk_f32_fp8(v3.y, false); acc[4] += e[0]; acc[5] += e[1];
        e = __builtin_amdgcn_cvt_pk_f32_fp8(v3.y, true);  acc[6] += e[0]; acc[7] += e[1];
    }
    for (; j < end; j += 4) {
        uint2 v0 = *(const uint2*)(h8 + (size_t)eidx[j] * HD + d0);
        f32x2 e;
        e = __builtin_amdgcn_cvt_pk_f32_fp8(v0.x, false); acc[0] += e[0]; acc[1] += e[1];
        e = __builtin_amdgcn_cvt_pk_f32_fp8(v0.x, true);  acc[2] += e[0]; acc[3] += e[1];
        e = __builtin_amdgcn_cvt_pk_f32_fp8(v0.y, false); acc[4] += e[0]; acc[5] += e[1];
        e = __builtin_amdgcn_cvt_pk_f32_fp8(v0.y, true);  acc[6] += e[0]; acc[7] += e[1];
    }
#pragma unroll
    for (int i = 0; i < 8; ++i) {
        acc[i] += __shfl_xor(acc[i], 16);
        acc[i] += __shfl_xor(acc[i], 32);
    }
    if (epar == 0) {
        float inv = (end > beg) ? 1.0f / (float)(end - beg) : 0.f;
        U4H8 o;
#pragma unroll
        for (int i = 0; i < 8; ++i) o.h[i] = (_Float16)(acc[i] * inv);
        *(uint4*)(msg + (size_t)node * K2 + HD + d0) = o.u;
    }
}

// ---------------- SAGE layer: fp16 MFMA K=256; epilogue writes fp16 h + fp8 shadow ----------------
__global__ __launch_bounds__(256) void k_sage(const unsigned short* __restrict__ hin,  // [m][256] fp16
                                              const unsigned short* __restrict__ wt,   // [n][256] fp16
                                              const float* __restrict__ bias,
                                              unsigned short* __restrict__ hout,       // [m][256] h-part
                                              unsigned char* __restrict__ hout8) {     // [m][128] fp8
    __shared__ _Float16 Ah[128 * 40];   // stride 40 halfs (80 B): 2-way bank alias = free
    __shared__ _Float16 Bw[128 * 40];
    const int tid = threadIdx.x;
    const int wv = tid >> 6, lane = tid & 63;
    const int m0 = blockIdx.x * 128;
    const int m_off = (wv >> 1) * 64, n_off = (wv & 1) * 64;
    const int l15 = lane & 15, q = lane >> 4;

    f32x4 acc[4][4];
#pragma unroll
    for (int a = 0; a < 4; ++a)
#pragma unroll
        for (int b = 0; b < 4; ++b) acc[a][b] = (f32x4){0.f, 0.f, 0.f, 0.f};

#pragma unroll 1
    for (int kt = 0; kt < 8; ++kt) {
        const int k0 = kt * 32;
#pragma unroll
        for (int i = 0; i < 2; ++i) {
            int idx = tid + i * 256;
            int row = idx >> 2, kq = (idx & 3) * 8;
            int gm = m0 + row;
            uint4 va = make_uint4(0u, 0u, 0u, 0u);
            if (gm < N_NODES) va = *(const uint4*)(hin + (size_t)gm * K2 + k0 + kq);
            *(uint4*)&Ah[row * 40 + kq] = va;
            *(uint4*)&Bw[row * 40 + kq] = *(const uint4*)(wt + (size_t)row * K2 + k0 + kq);
        }
        __syncthreads();
        f16x8 hf[4], wf[4];
#pragma unroll
        for (int mt = 0; mt < 4; ++mt)
            hf[mt] = *(const f16x8*)&Ah[(m_off + mt * 16 + l15) * 40 + q * 8];
#pragma unroll
        for (int nt = 0; nt < 4; ++nt)
            wf[nt] = *(const f16x8*)&Bw[(n_off + nt * 16 + l15) * 40 + q * 8];
#pragma unroll
        for (int mt = 0; mt < 4; ++mt)
#pragma unroll
            for (int nt = 0; nt < 4; ++nt)
                acc[mt][nt] = __builtin_amdgcn_mfma_f32_16x16x32_f16(wf[nt], hf[mt], acc[mt][nt], 0, 0, 0);
        __syncthreads();
    }
#pragma unroll
    for (int nt = 0; nt < 4; ++nt) {
        int n = n_off + nt * 16 + q * 4;
        float4 bv = *(const float4*)(bias + n);
#pragma unroll
        for (int mt = 0; mt < 4; ++mt) {
            int m = m0 + m_off + mt * 16 + l15;
            if (m < N_NODES) {
                f32x4 a = acc[mt][nt];
                float r0 = fmaxf(a[0] + bv.x, 0.f);
                float r1 = fmaxf(a[1] + bv.y, 0.f);
                float r2 = fmaxf(a[2] + bv.z, 0.f);
                float r3 = fmaxf(a[3] + bv.w, 0.f);
                U2H4 v;
                v.h[0] = (_Float16)r0; v.h[1] = (_Float16)r1;
                v.h[2] = (_Float16)r2; v.h[3] = (_Float16)r3;
                *(uint2*)(hout + (size_t)m * K2 + n) = v.u;
                int p = __builtin_amdgcn_cvt_pk_fp8_f32(r0, r1, 0, false);
                p = __builtin_amdgcn_cvt_pk_fp8_f32(r2, r3, p, true);
                *(unsigned int*)(hout8 + (size_t)m * HD + n) = (unsigned)p;
            }
        }
    }
}

// ---------------- graph mean-pool + fused classifier (completion counter) ----------------
__global__ __launch_bounds__(256) void k_pool(const unsigned short* __restrict__ h,
                                              const int* __restrict__ gid,
                                              float* __restrict__ pooled,
                                              int* __restrict__ done,
                                              const float* __restrict__ counts,
                                              const float* __restrict__ Wf,
                                              const float* __restrict__ bf,
                                              float* __restrict__ out) {
    int d = threadIdx.x & 127;
    int half = threadIdx.x >> 7;
    int n0 = blockIdx.x * 128;
    float acc = 0.f;
    int cur = -1;
    for (int i = half; i < 128; i += 2) {
        int n = n0 + i;
        if (n >= N_NODES) break;
        int g = gid[n];
        if (g != cur) {
            if (cur >= 0) atomicAdd(&pooled[(size_t)cur * HD + d], acc);
            acc = 0.f;
            cur = g;
        }
        acc += h2f(h[(size_t)n * K2 + d]);
    }
    if (cur >= 0) atomicAdd(&pooled[(size_t)cur * HD + d], acc);

    __shared__ int is_last;
    __threadfence();
    __syncthreads();
    if (threadIdx.x == 0) {
        int old = atomicAdd(done, 1);
        is_last = (old == NB_POOL - 1);
    }
    __syncthreads();
    if (!is_last) return;
    __threadfence();
    for (int t = threadIdx.x; t < N_GRAPHS * CLS; t += 256) {
        int g = t / CLS, c = t % CLS;
        float inv = 1.0f / fmaxf(counts[g], 1.0f);
        float s = 0.f;
        for (int k = 0; k < HD; ++k) s += pooled[(size_t)g * HD + k] * Wf[k * CLS + c];
        out[t] = s * inv + bf[c];
    }
}

extern "C" void kernel_launch(void* const* d_in, const int* in_sizes, int n_in,
                              void* d_out, int out_size, void* d_ws, size_t ws_size,
                              hipStream_t stream) {
    const float* features = (const float*)d_in[0];
    const int*   esrc     = (const int*)d_in[1];
    const int*   edst     = (const int*)d_in[2];
    const int*   gids     = (const int*)d_in[3];
    const float* bs[3]  = {(const float*)d_in[6], (const float*)d_in[9], (const float*)d_in[12]};
    const float* Wf = (const float*)d_in[13];
    const float* bfv = (const float*)d_in[14];
    float* out = (float*)d_out;

    int* deg_i  = (int*)d_ws;            // 50000 + gcount(8) + done(1), zeroed as 50064 block
    int* gcount = deg_i + 50000;
    int* done   = deg_i + 50008;
    int* rowptr = deg_i + 50064;
    int* cursor = rowptr + 50064;
    int* bsum   = cursor + 50048;
    int* eidx   = bsum + 256;
    int2* stag  = (int2*)(eidx + 800000);
    float* pooled = (float*)(stag + (size_t)NPART * PCAP);
    float* counts = pooled + N_GRAPHS * HD;
    unsigned short* C0 = (unsigned short*)(counts + 128);    // 50000*256 fp16 x3 (h|msg)
    unsigned short* C1 = C0 + (size_t)N_NODES * K2;
    unsigned short* C2 = C1 + (size_t)N_NODES * K2;
    unsigned short* Wt = C2 + (size_t)N_NODES * K2;
    unsigned char* F0 = (unsigned char*)(Wt + 3 * HD * K2);
    unsigned char* F1 = F0 + (size_t)N_NODES * HD;
    unsigned char* F2 = F1 + (size_t)N_NODES * HD;

    k_init<<<(INIT_THREADS + 255) / 256, 256, 0, stream>>>(
        features, C0, F0,
        (const float*)d_in[4], (const float*)d_in[5],
        (const float*)d_in[7], (const float*)d_in[8],
        (const float*)d_in[10], (const float*)d_in[11],
        Wt, deg_i, pooled, gids, counts);

    k_bin<<<NBIN, 256, 0, stream>>>(esrc, edst, stag, gcount);
    k_deg2<<<NPART * 64, 256, 0, stream>>>(stag, gcount, deg_i);
    k_scan_part<<<NB_SCAN, 256, 0, stream>>>(deg_i, rowptr, bsum);
    k_scan_add<<<NB_SCAN, 256, 0, stream>>>(rowptr, bsum, cursor);
    k_fill2<<<NPART * 64, 256, 0, stream>>>(stag, gcount, cursor, eidx);

    unsigned short* C[4] = {C0, C1, C2, C0};
    unsigned char* F[4] = {F0, F1, F2, F0};
    for (int l = 0; l < 3; ++l) {
        k_gather<<<(N_NODES * 64 + 255) / 256, 256, 0, stream>>>(F[l], rowptr, eidx, C[l]);
        k_sage<<<(N_NODES + 127) / 128, 256, 0, stream>>>(
            C[l], Wt + (size_t)l * HD * K2, bs[l], C[l + 1], F[l + 1]);
    }

    k_pool<<<NB_POOL, 256, 0, stream>>>(C0, gids, pooled, done, counts, Wf, bfv, out);
}

// Round 14
// 377.007 us; speedup vs baseline: 1.4009x; 1.1081x over previous
//
#include <hip/hip_runtime.h>

#define N_NODES  50000
#define N_EDGES  800000
#define N_GRAPHS 128
#define HD       128
#define K2       256
#define CLS      10
#define NB_SCAN  ((N_NODES + 255) / 256)    // 196
#define NPART    8
#define PSIZE    (N_NODES / NPART)          // 6250
#define NBIN     400
#define CHUNK    (N_EDGES / NBIN)           // 2000
#define PCAP     131072

typedef __attribute__((ext_vector_type(8))) _Float16 f16x8;
typedef __attribute__((ext_vector_type(4))) float f32x4;
typedef __attribute__((ext_vector_type(2))) float f32x2;

union U4H8 { uint4 u; _Float16 h[8]; };
union U2H4 { uint2 u; _Float16 h[4]; };

__device__ inline float h2f(unsigned short s) {
    union { unsigned short u; _Float16 h; } c; c.u = s; return (float)c.h;
}

// ---------------- init: cast features (fp16 + fp8), prep weights, zero deg/gcount/pooled, counts ----------------
__global__ __launch_bounds__(256) void k_init(const float* __restrict__ f,
                                              unsigned short* __restrict__ c0, unsigned char* __restrict__ f8,
                                              const float* __restrict__ Ws0, const float* __restrict__ Wn0,
                                              const float* __restrict__ Ws1, const float* __restrict__ Wn1,
                                              const float* __restrict__ Ws2, const float* __restrict__ Wn2,
                                              unsigned short* __restrict__ wt,
                                              int* __restrict__ zero_region, float* __restrict__ pooled,
                                              const int* __restrict__ gid, float* __restrict__ counts) {
    long long gi = (long long)blockIdx.x * 256 + threadIdx.x;
    if (gi < 800000) {   // features: 8 elems/thread -> fp16 (K2-strided h-part) + fp8 row
        int t = (int)gi;
        int row = t >> 4, c8 = (t & 15) * 8;
        const float* p = f + (size_t)row * HD + c8;
        float4 a = *(const float4*)p;
        float4 b = *(const float4*)(p + 4);
        U4H8 v;
        v.h[0] = (_Float16)a.x; v.h[1] = (_Float16)a.y;
        v.h[2] = (_Float16)a.z; v.h[3] = (_Float16)a.w;
        v.h[4] = (_Float16)b.x; v.h[5] = (_Float16)b.y;
        v.h[6] = (_Float16)b.z; v.h[7] = (_Float16)b.w;
        *(uint4*)(c0 + (size_t)row * K2 + c8) = v.u;
        int p0 = __builtin_amdgcn_cvt_pk_fp8_f32(a.x, a.y, 0, false);
        p0 = __builtin_amdgcn_cvt_pk_fp8_f32(a.z, a.w, p0, true);
        int p1 = __builtin_amdgcn_cvt_pk_fp8_f32(b.x, b.y, 0, false);
        p1 = __builtin_amdgcn_cvt_pk_fp8_f32(b.z, b.w, p1, true);
        *(uint2*)(f8 + (size_t)row * HD + c8) = make_uint2((unsigned)p0, (unsigned)p1);
        return;
    }
    gi -= 800000;
    if (gi < 3 * HD * K2) {   // weights: transpose+concat -> fp16 [l][n][k]
        int t = (int)gi;
        int l = t / (HD * K2), r = t % (HD * K2);
        int n = r / K2, k = r % K2;
        const float* Ws = (l == 0) ? Ws0 : (l == 1) ? Ws1 : Ws2;
        const float* Wn = (l == 0) ? Wn0 : (l == 1) ? Wn1 : Wn2;
        float w = (k < HD) ? Ws[k * HD + n] : Wn[(k - HD) * HD + n];
        union { unsigned short u; _Float16 h; } c;
        c.h = (_Float16)w;
        wt[t] = c.u;
        return;
    }
    gi -= 3 * HD * K2;
    if (gi < 50064) { zero_region[gi] = 0; return; }   // deg + gcount
    gi -= 50064;
    if (gi < N_GRAPHS * HD) { pooled[gi] = 0.f; return; }
    gi -= (long long)N_GRAPHS * HD;
    if (gi < N_GRAPHS) {   // graph counts via binary search (gid sorted)
        int g = (int)gi;
        int lo = 0, hi = N_NODES;
        while (lo < hi) { int mid = (lo + hi) >> 1; if (gid[mid] < g) lo = mid + 1; else hi = mid; }
        int start = lo;
        lo = 0; hi = N_NODES;
        while (lo < hi) { int mid = (lo + hi) >> 1; if (gid[mid] <= g) lo = mid + 1; else hi = mid; }
        counts[g] = (float)(lo - start);
    }
}
#define INIT_THREADS (800000 + 3 * HD * K2 + 50064 + N_GRAPHS * HD + N_GRAPHS)

// ---------------- bin edges by dst partition (wave-aggregated LDS atomics) ----------------
__global__ __launch_bounds__(256) void k_bin(const int* __restrict__ src, const int* __restrict__ dst,
                                             int2* __restrict__ stag, int* __restrict__ gcount) {
    __shared__ int lcount[NPART];
    __shared__ int lbase[NPART];
    const int tid = threadIdx.x;
    const int lane = tid & 63;
    const int lo = blockIdx.x * CHUNK;
    if (tid < NPART) lcount[tid] = 0;
    __syncthreads();
    for (int i = lo + tid; i < lo + CHUNK; i += 256) {
        int p = dst[i] / PSIZE;
#pragma unroll
        for (int q = 0; q < NPART; ++q) {
            unsigned long long m = __ballot(p == q);
            if (p == q) {
                int leader = __ffsll((long long)m) - 1;
                if (lane == leader) atomicAdd(&lcount[q], (int)__popcll(m));
            }
        }
    }
    __syncthreads();
    if (tid < NPART) {
        lbase[tid] = atomicAdd(&gcount[tid], lcount[tid]);
        lcount[tid] = 0;   // reuse as cursor
    }
    __syncthreads();
    for (int i = lo + tid; i < lo + CHUNK; i += 256) {
        int d = dst[i];
        int p = d / PSIZE;
        int slot = 0;
#pragma unroll
        for (int q = 0; q < NPART; ++q) {
            unsigned long long m = __ballot(p == q);
            if (p == q) {
                int leader = __ffsll((long long)m) - 1;
                int rank = (int)__popcll(m & ((1ull << lane) - 1ull));
                int base;
                if (lane == leader) base = atomicAdd(&lcount[q], (int)__popcll(m));
                base = __shfl(base, leader);
                slot = base + rank;
            }
        }
        stag[(size_t)p * PCAP + lbase[p] + slot] = make_int2(src[i], d);
    }
}

// ---------------- degree count from staged pairs (XCD-local atomics) ----------------
__global__ __launch_bounds__(256) void k_deg2(const int2* __restrict__ stag, const int* __restrict__ gcount,
                                              int* __restrict__ deg) {
    const int part = blockIdx.x & (NPART - 1);
    const int blk = blockIdx.x >> 3;
    const int n = gcount[part];
    const int2* s = stag + (size_t)part * PCAP;
    for (int i = blk * 256 + threadIdx.x; i < n; i += 64 * 256)
        atomicAdd(&deg[s[i].y], 1);
}

// ---------------- CSR fill from staged pairs (XCD-local) ----------------
__global__ __launch_bounds__(256) void k_fill2(const int2* __restrict__ stag, const int* __restrict__ gcount,
                                               int* __restrict__ cursor, int* __restrict__ eidx) {
    const int part = blockIdx.x & (NPART - 1);
    const int blk = blockIdx.x >> 3;
    const int n = gcount[part];
    const int2* s = stag + (size_t)part * PCAP;
    for (int i = blk * 256 + threadIdx.x; i < n; i += 64 * 256) {
        int2 e = s[i];
        int pos = atomicAdd(&cursor[e.y], 1);
        eidx[pos] = e.x;
    }
}

// ---------------- scan phase 1: per-block local exclusive scan ----------------
__global__ __launch_bounds__(256) void k_scan_part(const int* __restrict__ deg,
                                                   int* __restrict__ rowptr, int* __restrict__ bsum) {
    __shared__ int s[256];
    const int tid = threadIdx.x;
    const int i = blockIdx.x * 256 + tid;
    int v = (i < N_NODES) ? deg[i] : 0;
    s[tid] = v;
    __syncthreads();
    for (int off = 1; off < 256; off <<= 1) {
        int add = (tid >= off) ? s[tid - off] : 0;
        __syncthreads();
        s[tid] += add;
        __syncthreads();
    }
    if (i < N_NODES) rowptr[i] = s[tid] - v;
    if (tid == 255) bsum[blockIdx.x] = s[255];
}

// ---------------- scan phase 2: redundant top-scan per block + add offsets ----------------
__global__ __launch_bounds__(256) void k_scan_add(int* __restrict__ rowptr, const int* __restrict__ bsum,
                                                  int* __restrict__ cursor) {
    __shared__ int s[256];
    __shared__ int off_sh;
    const int tid = threadIdx.x;
    int v = (tid < NB_SCAN) ? bsum[tid] : 0;
    s[tid] = v;
    __syncthreads();
    for (int off = 1; off < 256; off <<= 1) {
        int add = (tid >= off) ? s[tid - off] : 0;
        __syncthreads();
        s[tid] += add;
        __syncthreads();
    }
    if (tid == blockIdx.x) off_sh = s[tid] - v;
    __syncthreads();
    const int i = blockIdx.x * 256 + tid;
    if (i < N_NODES) {
        int r = rowptr[i] + off_sh;
        rowptr[i] = r;
        cursor[i] = r;
    }
    if (blockIdx.x == 0 && tid == 0) rowptr[N_NODES] = N_EDGES;
}

// ---------------- gather: one wave per node, fp8 rows, fp32 accum, 16 edges in flight ----------------
__global__ __launch_bounds__(256) void k_gather(const unsigned char* __restrict__ h8,
                                                const int* __restrict__ rowptr,
                                                const int* __restrict__ eidx,
                                                unsigned short* __restrict__ msg) {
    const int node = (blockIdx.x * 256 + threadIdx.x) >> 6;
    const int lane = threadIdx.x & 63;
    if (node >= N_NODES) return;
    const int epar = lane >> 4;        // 4 edge slots
    const int d0 = (lane & 15) * 8;    // 8 fp8 per lane = 8 B
    const int beg = rowptr[node], end = rowptr[node + 1];
    float acc[8] = {0.f, 0.f, 0.f, 0.f, 0.f, 0.f, 0.f, 0.f};
    int j = beg + epar;
    for (; j + 12 < end; j += 16) {    // 16 edges in flight per wave
        int s0 = eidx[j], s1 = eidx[j + 4], s2 = eidx[j + 8], s3 = eidx[j + 12];
        uint2 v0 = *(const uint2*)(h8 + (size_t)s0 * HD + d0);
        uint2 v1 = *(const uint2*)(h8 + (size_t)s1 * HD + d0);
        uint2 v2 = *(const uint2*)(h8 + (size_t)s2 * HD + d0);
        uint2 v3 = *(const uint2*)(h8 + (size_t)s3 * HD + d0);
        f32x2 e;
        e = __builtin_amdgcn_cvt_pk_f32_fp8(v0.x, false); acc[0] += e[0]; acc[1] += e[1];
        e = __builtin_amdgcn_cvt_pk_f32_fp8(v0.x, true);  acc[2] += e[0]; acc[3] += e[1];
        e = __builtin_amdgcn_cvt_pk_f32_fp8(v0.y, false); acc[4] += e[0]; acc[5] += e[1];
        e = __builtin_amdgcn_cvt_pk_f32_fp8(v0.y, true);  acc[6] += e[0]; acc[7] += e[1];
        e = __builtin_amdgcn_cvt_pk_f32_fp8(v1.x, false); acc[0] += e[0]; acc[1] += e[1];
        e = __builtin_amdgcn_cvt_pk_f32_fp8(v1.x, true);  acc[2] += e[0]; acc[3] += e[1];
        e = __builtin_amdgcn_cvt_pk_f32_fp8(v1.y, false); acc[4] += e[0]; acc[5] += e[1];
        e = __builtin_amdgcn_cvt_pk_f32_fp8(v1.y, true);  acc[6] += e[0]; acc[7] += e[1];
        e = __builtin_amdgcn_cvt_pk_f32_fp8(v2.x, false); acc[0] += e[0]; acc[1] += e[1];
        e = __builtin_amdgcn_cvt_pk_f32_fp8(v2.x, true);  acc[2] += e[0]; acc[3] += e[1];
        e = __builtin_amdgcn_cvt_pk_f32_fp8(v2.y, false); acc[4] += e[0]; acc[5] += e[1];
        e = __builtin_amdgcn_cvt_pk_f32_fp8(v2.y, true);  acc[6] += e[0]; acc[7] += e[1];
        e = __builtin_amdgcn_cvt_pk_f32_fp8(v3.x, false); acc[0] += e[0]; acc[1] += e[1];
        e = __builtin_amdgcn_cvt_pk_f32_fp8(v3.x, true);  acc[2] += e[0]; acc[3] += e[1];
        e = __builtin_amdgcn_cvt_pk_f32_fp8(v3.y, false); acc[4] += e[0]; acc[5] += e[1];
        e = __builtin_amdgcn_cvt_pk_f32_fp8(v3.y, true);  acc[6] += e[0]; acc[7] += e[1];
    }
    for (; j < end; j += 4) {
        uint2 v0 = *(const uint2*)(h8 + (size_t)eidx[j] * HD + d0);
        f32x2 e;
        e = __builtin_amdgcn_cvt_pk_f32_fp8(v0.x, false); acc[0] += e[0]; acc[1] += e[1];
        e = __builtin_amdgcn_cvt_pk_f32_fp8(v0.x, true);  acc[2] += e[0]; acc[3] += e[1];
        e = __builtin_amdgcn_cvt_pk_f32_fp8(v0.y, false); acc[4] += e[0]; acc[5] += e[1];
        e = __builtin_amdgcn_cvt_pk_f32_fp8(v0.y, true);  acc[6] += e[0]; acc[7] += e[1];
    }
#pragma unroll
    for (int i = 0; i < 8; ++i) {
        acc[i] += __shfl_xor(acc[i], 16);
        acc[i] += __shfl_xor(acc[i], 32);
    }
    if (epar == 0) {
        float inv = (end > beg) ? 1.0f / (float)(end - beg) : 0.f;
        U4H8 o;
#pragma unroll
        for (int i = 0; i < 8; ++i) o.h[i] = (_Float16)(acc[i] * inv);
        *(uint4*)(msg + (size_t)node * K2 + HD + d0) = o.u;
    }
}

// ---------------- SAGE layer: fp16 MFMA K=256; epilogue writes fp16 h + fp8 shadow ----------------
__global__ __launch_bounds__(256) void k_sage(const unsigned short* __restrict__ hin,  // [m][256] fp16
                                              const unsigned short* __restrict__ wt,   // [n][256] fp16
                                              const float* __restrict__ bias,
                                              unsigned short* __restrict__ hout,       // [m][256] h-part
                                              unsigned char* __restrict__ hout8) {     // [m][128] fp8
    __shared__ _Float16 Ah[128 * 40];   // stride 40 halfs (80 B): 2-way bank alias = free
    __shared__ _Float16 Bw[128 * 40];
    const int tid = threadIdx.x;
    const int wv = tid >> 6, lane = tid & 63;
    const int m0 = blockIdx.x * 128;
    const int m_off = (wv >> 1) * 64, n_off = (wv & 1) * 64;
    const int l15 = lane & 15, q = lane >> 4;

    f32x4 acc[4][4];
#pragma unroll
    for (int a = 0; a < 4; ++a)
#pragma unroll
        for (int b = 0; b < 4; ++b) acc[a][b] = (f32x4){0.f, 0.f, 0.f, 0.f};

#pragma unroll 1
    for (int kt = 0; kt < 8; ++kt) {
        const int k0 = kt * 32;
#pragma unroll
        for (int i = 0; i < 2; ++i) {
            int idx = tid + i * 256;
            int row = idx >> 2, kq = (idx & 3) * 8;
            int gm = m0 + row;
            uint4 va = make_uint4(0u, 0u, 0u, 0u);
            if (gm < N_NODES) va = *(const uint4*)(hin + (size_t)gm * K2 + k0 + kq);
            *(uint4*)&Ah[row * 40 + kq] = va;
            *(uint4*)&Bw[row * 40 + kq] = *(const uint4*)(wt + (size_t)row * K2 + k0 + kq);
        }
        __syncthreads();
        f16x8 hf[4], wf[4];
#pragma unroll
        for (int mt = 0; mt < 4; ++mt)
            hf[mt] = *(const f16x8*)&Ah[(m_off + mt * 16 + l15) * 40 + q * 8];
#pragma unroll
        for (int nt = 0; nt < 4; ++nt)
            wf[nt] = *(const f16x8*)&Bw[(n_off + nt * 16 + l15) * 40 + q * 8];
#pragma unroll
        for (int mt = 0; mt < 4; ++mt)
#pragma unroll
            for (int nt = 0; nt < 4; ++nt)
                acc[mt][nt] = __builtin_amdgcn_mfma_f32_16x16x32_f16(wf[nt], hf[mt], acc[mt][nt], 0, 0, 0);
        __syncthreads();
    }
#pragma unroll
    for (int nt = 0; nt < 4; ++nt) {
        int n = n_off + nt * 16 + q * 4;
        float4 bv = *(const float4*)(bias + n);
#pragma unroll
        for (int mt = 0; mt < 4; ++mt) {
            int m = m0 + m_off + mt * 16 + l15;
            if (m < N_NODES) {
                f32x4 a = acc[mt][nt];
                float r0 = fmaxf(a[0] + bv.x, 0.f);
                float r1 = fmaxf(a[1] + bv.y, 0.f);
                float r2 = fmaxf(a[2] + bv.z, 0.f);
                float r3 = fmaxf(a[3] + bv.w, 0.f);
                U2H4 v;
                v.h[0] = (_Float16)r0; v.h[1] = (_Float16)r1;
                v.h[2] = (_Float16)r2; v.h[3] = (_Float16)r3;
                *(uint2*)(hout + (size_t)m * K2 + n) = v.u;
                int p = __builtin_amdgcn_cvt_pk_fp8_f32(r0, r1, 0, false);
                p = __builtin_amdgcn_cvt_pk_fp8_f32(r2, r3, p, true);
                *(unsigned int*)(hout8 + (size_t)m * HD + n) = (unsigned)p;
            }
        }
    }
}

// ---------------- graph mean-pool (fp16 h, sorted gids) ----------------
__global__ __launch_bounds__(256) void k_pool(const unsigned short* __restrict__ h,
                                              const int* __restrict__ gid,
                                              float* __restrict__ pooled) {
    int d = threadIdx.x & 127;
    int half = threadIdx.x >> 7;
    int n0 = blockIdx.x * 128;
    float acc = 0.f;
    int cur = -1;
    for (int i = half; i < 128; i += 2) {
        int n = n0 + i;
        if (n >= N_NODES) break;
        int g = gid[n];
        if (g != cur) {
            if (cur >= 0) atomicAdd(&pooled[(size_t)cur * HD + d], acc);
            acc = 0.f;
            cur = g;
        }
        acc += h2f(h[(size_t)n * K2 + d]);
    }
    if (cur >= 0) atomicAdd(&pooled[(size_t)cur * HD + d], acc);
}

// ---------------- classifier (fp32) ----------------
__global__ __launch_bounds__(256) void k_final(const float* __restrict__ pooled,
                                               const float* __restrict__ counts,
                                               const float* __restrict__ Wf,
                                               const float* __restrict__ bf,
                                               float* __restrict__ out) {
    int t = blockIdx.x * 256 + threadIdx.x;
    if (t >= N_GRAPHS * CLS) return;
    int g = t / CLS, c = t % CLS;
    float inv = 1.0f / fmaxf(counts[g], 1.0f);
    float s = 0.f;
    for (int k = 0; k < HD; ++k) s += pooled[(size_t)g * HD + k] * Wf[k * CLS + c];
    out[t] = s * inv + bf[c];
}

extern "C" void kernel_launch(void* const* d_in, const int* in_sizes, int n_in,
                              void* d_out, int out_size, void* d_ws, size_t ws_size,
                              hipStream_t stream) {
    const float* features = (const float*)d_in[0];
    const int*   esrc     = (const int*)d_in[1];
    const int*   edst     = (const int*)d_in[2];
    const int*   gids     = (const int*)d_in[3];
    const float* bs[3]  = {(const float*)d_in[6], (const float*)d_in[9], (const float*)d_in[12]};
    const float* Wf = (const float*)d_in[13];
    const float* bfv = (const float*)d_in[14];
    float* out = (float*)d_out;

    int* deg_i  = (int*)d_ws;            // 50000 + gcount(8), zeroed as 50064 block
    int* gcount = deg_i + 50000;
    int* rowptr = deg_i + 50064;
    int* cursor = rowptr + 50064;
    int* bsum   = cursor + 50048;
    int* eidx   = bsum + 256;
    int2* stag  = (int2*)(eidx + 800000);
    float* pooled = (float*)(stag + (size_t)NPART * PCAP);
    float* counts = pooled + N_GRAPHS * HD;
    unsigned short* C0 = (unsigned short*)(counts + 128);    // 50000*256 fp16 x3 (h|msg)
    unsigned short* C1 = C0 + (size_t)N_NODES * K2;
    unsigned short* C2 = C1 + (size_t)N_NODES * K2;
    unsigned short* Wt = C2 + (size_t)N_NODES * K2;
    unsigned char* F0 = (unsigned char*)(Wt + 3 * HD * K2);
    unsigned char* F1 = F0 + (size_t)N_NODES * HD;
    unsigned char* F2 = F1 + (size_t)N_NODES * HD;

    k_init<<<(INIT_THREADS + 255) / 256, 256, 0, stream>>>(
        features, C0, F0,
        (const float*)d_in[4], (const float*)d_in[5],
        (const float*)d_in[7], (const float*)d_in[8],
        (const float*)d_in[10], (const float*)d_in[11],
        Wt, deg_i, pooled, gids, counts);

    k_bin<<<NBIN, 256, 0, stream>>>(esrc, edst, stag, gcount);
    k_deg2<<<NPART * 64, 256, 0, stream>>>(stag, gcount, deg_i);
    k_scan_part<<<NB_SCAN, 256, 0, stream>>>(deg_i, rowptr, bsum);
    k_scan_add<<<NB_SCAN, 256, 0, stream>>>(rowptr, bsum, cursor);
    k_fill2<<<NPART * 64, 256, 0, stream>>>(stag, gcount, cursor, eidx);

    unsigned short* C[4] = {C0, C1, C2, C0};
    unsigned char* F[4] = {F0, F1, F2, F0};
    for (int l = 0; l < 3; ++l) {
        k_gather<<<(N_NODES * 64 + 255) / 256, 256, 0, stream>>>(F[l], rowptr, eidx, C[l]);
        k_sage<<<(N_NODES + 127) / 128, 256, 0, stream>>>(
            C[l], Wt + (size_t)l * HD * K2, bs[l], C[l + 1], F[l + 1]);
    }

    k_pool<<<(N_NODES + 127) / 128, 256, 0, stream>>>(C0, gids, pooled);
    k_final<<<(N_GRAPHS * CLS + 255) / 256, 256, 0, stream>>>(pooled, counts, Wf, bfv, out);
}

// Round 15
// 361.562 us; speedup vs baseline: 1.4607x; 1.0427x over previous
//
#include <hip/hip_runtime.h>

#define N_NODES  50000
#define N_EDGES  800000
#define N_GRAPHS 128
#define HD       128
#define K2       256
#define CLS      10
#define NB_SCAN  ((N_NODES + 255) / 256)    // 196
#define NPART    8
#define PSIZE    (N_NODES / NPART)          // 6250
#define NBIN     400
#define CHUNK    (N_EDGES / NBIN)           // 2000
#define PCAP     131072

typedef __attribute__((ext_vector_type(8))) _Float16 f16x8;
typedef __attribute__((ext_vector_type(4))) float f32x4;
typedef __attribute__((ext_vector_type(2))) float f32x2;

union U4H8 { uint4 u; _Float16 h[8]; };
union U2H4 { uint2 u; _Float16 h[4]; };

__device__ inline float h2f(unsigned short s) {
    union { unsigned short u; _Float16 h; } c; c.u = s; return (float)c.h;
}

// ---------------- init: cast features (fp16 + fp8), prep weights, zero deg/gcount/pooled, counts ----------------
__global__ __launch_bounds__(256) void k_init(const float* __restrict__ f,
                                              unsigned short* __restrict__ c0, unsigned char* __restrict__ f8,
                                              const float* __restrict__ Ws0, const float* __restrict__ Wn0,
                                              const float* __restrict__ Ws1, const float* __restrict__ Wn1,
                                              const float* __restrict__ Ws2, const float* __restrict__ Wn2,
                                              unsigned short* __restrict__ wt,
                                              int* __restrict__ zero_region, float* __restrict__ pooled,
                                              const int* __restrict__ gid, float* __restrict__ counts) {
    long long gi = (long long)blockIdx.x * 256 + threadIdx.x;
    if (gi < 800000) {   // features: 8 elems/thread -> fp16 (K2-strided h-part) + fp8 row
        int t = (int)gi;
        int row = t >> 4, c8 = (t & 15) * 8;
        const float* p = f + (size_t)row * HD + c8;
        float4 a = *(const float4*)p;
        float4 b = *(const float4*)(p + 4);
        U4H8 v;
        v.h[0] = (_Float16)a.x; v.h[1] = (_Float16)a.y;
        v.h[2] = (_Float16)a.z; v.h[3] = (_Float16)a.w;
        v.h[4] = (_Float16)b.x; v.h[5] = (_Float16)b.y;
        v.h[6] = (_Float16)b.z; v.h[7] = (_Float16)b.w;
        *(uint4*)(c0 + (size_t)row * K2 + c8) = v.u;
        int p0 = __builtin_amdgcn_cvt_pk_fp8_f32(a.x, a.y, 0, false);
        p0 = __builtin_amdgcn_cvt_pk_fp8_f32(a.z, a.w, p0, true);
        int p1 = __builtin_amdgcn_cvt_pk_fp8_f32(b.x, b.y, 0, false);
        p1 = __builtin_amdgcn_cvt_pk_fp8_f32(b.z, b.w, p1, true);
        *(uint2*)(f8 + (size_t)row * HD + c8) = make_uint2((unsigned)p0, (unsigned)p1);
        return;
    }
    gi -= 800000;
    if (gi < 3 * HD * K2) {   // weights: transpose+concat -> fp16 [l][n][k]
        int t = (int)gi;
        int l = t / (HD * K2), r = t % (HD * K2);
        int n = r / K2, k = r % K2;
        const float* Ws = (l == 0) ? Ws0 : (l == 1) ? Ws1 : Ws2;
        const float* Wn = (l == 0) ? Wn0 : (l == 1) ? Wn1 : Wn2;
        float w = (k < HD) ? Ws[k * HD + n] : Wn[(k - HD) * HD + n];
        union { unsigned short u; _Float16 h; } c;
        c.h = (_Float16)w;
        wt[t] = c.u;
        return;
    }
    gi -= 3 * HD * K2;
    if (gi < 50064) { zero_region[gi] = 0; return; }   // deg + gcount
    gi -= 50064;
    if (gi < N_GRAPHS * HD) { pooled[gi] = 0.f; return; }
    gi -= (long long)N_GRAPHS * HD;
    if (gi < N_GRAPHS) {   // graph counts via binary search (gid sorted)
        int g = (int)gi;
        int lo = 0, hi = N_NODES;
        while (lo < hi) { int mid = (lo + hi) >> 1; if (gid[mid] < g) lo = mid + 1; else hi = mid; }
        int start = lo;
        lo = 0; hi = N_NODES;
        while (lo < hi) { int mid = (lo + hi) >> 1; if (gid[mid] <= g) lo = mid + 1; else hi = mid; }
        counts[g] = (float)(lo - start);
    }
}
#define INIT_THREADS (800000 + 3 * HD * K2 + 50064 + N_GRAPHS * HD + N_GRAPHS)

// ---------------- bin edges by dst partition (wave-aggregated LDS atomics) ----------------
__global__ __launch_bounds__(256) void k_bin(const int* __restrict__ src, const int* __restrict__ dst,
                                             int2* __restrict__ stag, int* __restrict__ gcount) {
    __shared__ int lcount[NPART];
    __shared__ int lbase[NPART];
    const int tid = threadIdx.x;
    const int lane = tid & 63;
    const int lo = blockIdx.x * CHUNK;
    if (tid < NPART) lcount[tid] = 0;
    __syncthreads();
    for (int i = lo + tid; i < lo + CHUNK; i += 256) {
        int p = dst[i] / PSIZE;
#pragma unroll
        for (int q = 0; q < NPART; ++q) {
            unsigned long long m = __ballot(p == q);
            if (p == q) {
                int leader = __ffsll((long long)m) - 1;
                if (lane == leader) atomicAdd(&lcount[q], (int)__popcll(m));
            }
        }
    }
    __syncthreads();
    if (tid < NPART) {
        lbase[tid] = atomicAdd(&gcount[tid], lcount[tid]);
        lcount[tid] = 0;   // reuse as cursor
    }
    __syncthreads();
    for (int i = lo + tid; i < lo + CHUNK; i += 256) {
        int d = dst[i];
        int p = d / PSIZE;
        int slot = 0;
#pragma unroll
        for (int q = 0; q < NPART; ++q) {
            unsigned long long m = __ballot(p == q);
            if (p == q) {
                int leader = __ffsll((long long)m) - 1;
                int rank = (int)__popcll(m & ((1ull << lane) - 1ull));
                int base;
                if (lane == leader) base = atomicAdd(&lcount[q], (int)__popcll(m));
                base = __shfl(base, leader);
                slot = base + rank;
            }
        }
        stag[(size_t)p * PCAP + lbase[p] + slot] = make_int2(src[i], d);
    }
}

// ---------------- degree count from staged pairs (XCD-local atomics) ----------------
__global__ __launch_bounds__(256) void k_deg2(const int2* __restrict__ stag, const int* __restrict__ gcount,
                                              int* __restrict__ deg) {
    const int part = blockIdx.x & (NPART - 1);
    const int blk = blockIdx.x >> 3;
    const int n = gcount[part];
    const int2* s = stag + (size_t)part * PCAP;
    for (int i = blk * 256 + threadIdx.x; i < n; i += 64 * 256)
        atomicAdd(&deg[s[i].y], 1);
}

// ---------------- CSR fill from staged pairs (XCD-local) ----------------
__global__ __launch_bounds__(256) void k_fill2(const int2* __restrict__ stag, const int* __restrict__ gcount,
                                               int* __restrict__ cursor, int* __restrict__ eidx) {
    const int part = blockIdx.x & (NPART - 1);
    const int blk = blockIdx.x >> 3;
    const int n = gcount[part];
    const int2* s = stag + (size_t)part * PCAP;
    for (int i = blk * 256 + threadIdx.x; i < n; i += 64 * 256) {
        int2 e = s[i];
        int pos = atomicAdd(&cursor[e.y], 1);
        eidx[pos] = e.x;
    }
}

// ---------------- scan phase 1: per-block local exclusive scan ----------------
__global__ __launch_bounds__(256) void k_scan_part(const int* __restrict__ deg,
                                                   int* __restrict__ rowptr, int* __restrict__ bsum) {
    __shared__ int s[256];
    const int tid = threadIdx.x;
    const int i = blockIdx.x * 256 + tid;
    int v = (i < N_NODES) ? deg[i] : 0;
    s[tid] = v;
    __syncthreads();
    for (int off = 1; off < 256; off <<= 1) {
        int add = (tid >= off) ? s[tid - off] : 0;
        __syncthreads();
        s[tid] += add;
        __syncthreads();
    }
    if (i < N_NODES) rowptr[i] = s[tid] - v;
    if (tid == 255) bsum[blockIdx.x] = s[255];
}

// ---------------- scan phase 2: redundant top-scan per block + add offsets ----------------
__global__ __launch_bounds__(256) void k_scan_add(int* __restrict__ rowptr, const int* __restrict__ bsum,
                                                  int* __restrict__ cursor) {
    __shared__ int s[256];
    __shared__ int off_sh;
    const int tid = threadIdx.x;
    int v = (tid < NB_SCAN) ? bsum[tid] : 0;
    s[tid] = v;
    __syncthreads();
    for (int off = 1; off < 256; off <<= 1) {
        int add = (tid >= off) ? s[tid - off] : 0;
        __syncthreads();
        s[tid] += add;
        __syncthreads();
    }
    if (tid == blockIdx.x) off_sh = s[tid] - v;
    __syncthreads();
    const int i = blockIdx.x * 256 + tid;
    if (i < N_NODES) {
        int r = rowptr[i] + off_sh;
        rowptr[i] = r;
        cursor[i] = r;
    }
    if (blockIdx.x == 0 && tid == 0) rowptr[N_NODES] = N_EDGES;
}

// ---------------- gather: one wave per node, fp8 rows, fp32 accum, 16 edges in flight ----------------
__global__ __launch_bounds__(256) void k_gather(const unsigned char* __restrict__ h8,
                                                const int* __restrict__ rowptr,
                                                const int* __restrict__ eidx,
                                                unsigned short* __restrict__ msg) {
    const int node = (blockIdx.x * 256 + threadIdx.x) >> 6;
    const int lane = threadIdx.x & 63;
    if (node >= N_NODES) return;
    const int epar = lane >> 4;        // 4 edge slots
    const int d0 = (lane & 15) * 8;    // 8 fp8 per lane = 8 B
    const int beg = rowptr[node], end = rowptr[node + 1];
    float acc[8] = {0.f, 0.f, 0.f, 0.f, 0.f, 0.f, 0.f, 0.f};
    int j = beg + epar;
    for (; j + 12 < end; j += 16) {    // 16 edges in flight per wave
        int s0 = eidx[j], s1 = eidx[j + 4], s2 = eidx[j + 8], s3 = eidx[j + 12];
        uint2 v0 = *(const uint2*)(h8 + (size_t)s0 * HD + d0);
        uint2 v1 = *(const uint2*)(h8 + (size_t)s1 * HD + d0);
        uint2 v2 = *(const uint2*)(h8 + (size_t)s2 * HD + d0);
        uint2 v3 = *(const uint2*)(h8 + (size_t)s3 * HD + d0);
        f32x2 e;
        e = __builtin_amdgcn_cvt_pk_f32_fp8(v0.x, false); acc[0] += e[0]; acc[1] += e[1];
        e = __builtin_amdgcn_cvt_pk_f32_fp8(v0.x, true);  acc[2] += e[0]; acc[3] += e[1];
        e = __builtin_amdgcn_cvt_pk_f32_fp8(v0.y, false); acc[4] += e[0]; acc[5] += e[1];
        e = __builtin_amdgcn_cvt_pk_f32_fp8(v0.y, true);  acc[6] += e[0]; acc[7] += e[1];
        e = __builtin_amdgcn_cvt_pk_f32_fp8(v1.x, false); acc[0] += e[0]; acc[1] += e[1];
        e = __builtin_amdgcn_cvt_pk_f32_fp8(v1.x, true);  acc[2] += e[0]; acc[3] += e[1];
        e = __builtin_amdgcn_cvt_pk_f32_fp8(v1.y, false); acc[4] += e[0]; acc[5] += e[1];
        e = __builtin_amdgcn_cvt_pk_f32_fp8(v1.y, true);  acc[6] += e[0]; acc[7] += e[1];
        e = __builtin_amdgcn_cvt_pk_f32_fp8(v2.x, false); acc[0] += e[0]; acc[1] += e[1];
        e = __builtin_amdgcn_cvt_pk_f32_fp8(v2.x, true);  acc[2] += e[0]; acc[3] += e[1];
        e = __builtin_amdgcn_cvt_pk_f32_fp8(v2.y, false); acc[4] += e[0]; acc[5] += e[1];
        e = __builtin_amdgcn_cvt_pk_f32_fp8(v2.y, true);  acc[6] += e[0]; acc[7] += e[1];
        e = __builtin_amdgcn_cvt_pk_f32_fp8(v3.x, false); acc[0] += e[0]; acc[1] += e[1];
        e = __builtin_amdgcn_cvt_pk_f32_fp8(v3.x, true);  acc[2] += e[0]; acc[3] += e[1];
        e = __builtin_amdgcn_cvt_pk_f32_fp8(v3.y, false); acc[4] += e[0]; acc[5] += e[1];
        e = __builtin_amdgcn_cvt_pk_f32_fp8(v3.y, true);  acc[6] += e[0]; acc[7] += e[1];
    }
    for (; j < end; j += 4) {
        uint2 v0 = *(const uint2*)(h8 + (size_t)eidx[j] * HD + d0);
        f32x2 e;
        e = __builtin_amdgcn_cvt_pk_f32_fp8(v0.x, false); acc[0] += e[0]; acc[1] += e[1];
        e = __builtin_amdgcn_cvt_pk_f32_fp8(v0.x, true);  acc[2] += e[0]; acc[3] += e[1];
        e = __builtin_amdgcn_cvt_pk_f32_fp8(v0.y, false); acc[4] += e[0]; acc[5] += e[1];
        e = __builtin_amdgcn_cvt_pk_f32_fp8(v0.y, true);  acc[6] += e[0]; acc[7] += e[1];
    }
#pragma unroll
    for (int i = 0; i < 8; ++i) {
        acc[i] += __shfl_xor(acc[i], 16);
        acc[i] += __shfl_xor(acc[i], 32);
    }
    if (epar == 0) {
        float inv = (end > beg) ? 1.0f / (float)(end - beg) : 0.f;
        U4H8 o;
#pragma unroll
        for (int i = 0; i < 8; ++i) o.h[i] = (_Float16)(acc[i] * inv);
        *(uint4*)(msg + (size_t)node * K2 + HD + d0) = o.u;
    }
}

// ---------------- SAGE layer: fp16 MFMA K=256; epilogue writes fp16 h (optional) + fp8 shadow ----------------
__global__ __launch_bounds__(256) void k_sage(const unsigned short* __restrict__ hin,  // [m][256] fp16
                                              const unsigned short* __restrict__ wt,   // [n][256] fp16
                                              const float* __restrict__ bias,
                                              unsigned short* __restrict__ hout,       // [m][256] h-part
                                              unsigned char* __restrict__ hout8,       // [m][128] fp8
                                              int write16) {
    __shared__ _Float16 Ah[128 * 40];   // stride 40 halfs (80 B): 2-way bank alias = free
    __shared__ _Float16 Bw[128 * 40];
    const int tid = threadIdx.x;
    const int wv = tid >> 6, lane = tid & 63;
    const int m0 = blockIdx.x * 128;
    const int m_off = (wv >> 1) * 64, n_off = (wv & 1) * 64;
    const int l15 = lane & 15, q = lane >> 4;

    f32x4 acc[4][4];
#pragma unroll
    for (int a = 0; a < 4; ++a)
#pragma unroll
        for (int b = 0; b < 4; ++b) acc[a][b] = (f32x4){0.f, 0.f, 0.f, 0.f};

#pragma unroll 1
    for (int kt = 0; kt < 8; ++kt) {
        const int k0 = kt * 32;
#pragma unroll
        for (int i = 0; i < 2; ++i) {
            int idx = tid + i * 256;
            int row = idx >> 2, kq = (idx & 3) * 8;
            int gm = m0 + row;
            uint4 va = make_uint4(0u, 0u, 0u, 0u);
            if (gm < N_NODES) va = *(const uint4*)(hin + (size_t)gm * K2 + k0 + kq);
            *(uint4*)&Ah[row * 40 + kq] = va;
            *(uint4*)&Bw[row * 40 + kq] = *(const uint4*)(wt + (size_t)row * K2 + k0 + kq);
        }
        __syncthreads();
        f16x8 hf[4], wf[4];
#pragma unroll
        for (int mt = 0; mt < 4; ++mt)
            hf[mt] = *(const f16x8*)&Ah[(m_off + mt * 16 + l15) * 40 + q * 8];
#pragma unroll
        for (int nt = 0; nt < 4; ++nt)
            wf[nt] = *(const f16x8*)&Bw[(n_off + nt * 16 + l15) * 40 + q * 8];
#pragma unroll
        for (int mt = 0; mt < 4; ++mt)
#pragma unroll
            for (int nt = 0; nt < 4; ++nt)
                acc[mt][nt] = __builtin_amdgcn_mfma_f32_16x16x32_f16(wf[nt], hf[mt], acc[mt][nt], 0, 0, 0);
        __syncthreads();
    }
#pragma unroll
    for (int nt = 0; nt < 4; ++nt) {
        int n = n_off + nt * 16 + q * 4;
        float4 bv = *(const float4*)(bias + n);
#pragma unroll
        for (int mt = 0; mt < 4; ++mt) {
            int m = m0 + m_off + mt * 16 + l15;
            if (m < N_NODES) {
                f32x4 a = acc[mt][nt];
                float r0 = fmaxf(a[0] + bv.x, 0.f);
                float r1 = fmaxf(a[1] + bv.y, 0.f);
                float r2 = fmaxf(a[2] + bv.z, 0.f);
                float r3 = fmaxf(a[3] + bv.w, 0.f);
                if (write16) {
                    U2H4 v;
                    v.h[0] = (_Float16)r0; v.h[1] = (_Float16)r1;
                    v.h[2] = (_Float16)r2; v.h[3] = (_Float16)r3;
                    *(uint2*)(hout + (size_t)m * K2 + n) = v.u;
                }
                int p = __builtin_amdgcn_cvt_pk_fp8_f32(r0, r1, 0, false);
                p = __builtin_amdgcn_cvt_pk_fp8_f32(r2, r3, p, true);
                *(unsigned int*)(hout8 + (size_t)m * HD + n) = (unsigned)p;
            }
        }
    }
}

// ---------------- graph mean-pool from fp8 shadow (sorted gids) ----------------
// 4 node-slices x 64 dim-pairs; per-slice run-length accumulation
__global__ __launch_bounds__(256) void k_pool(const unsigned char* __restrict__ h8,
                                              const int* __restrict__ gid,
                                              float* __restrict__ pooled) {
    const int p2 = (threadIdx.x & 63) * 2;   // dim pair
    const int sl = threadIdx.x >> 6;         // node slice 0..3
    const int n0 = blockIdx.x * 128;
    float a0 = 0.f, a1 = 0.f;
    int cur = -1;
    for (int i = sl; i < 128; i += 4) {
        int n = n0 + i;
        if (n >= N_NODES) break;
        int g = gid[n];
        if (g != cur) {
            if (cur >= 0) {
                atomicAdd(&pooled[(size_t)cur * HD + p2], a0);
                atomicAdd(&pooled[(size_t)cur * HD + p2 + 1], a1);
            }
            a0 = 0.f; a1 = 0.f;
            cur = g;
        }
        unsigned short v = *(const unsigned short*)(h8 + (size_t)n * HD + p2);
        f32x2 e = __builtin_amdgcn_cvt_pk_f32_fp8((unsigned)v, false);
        a0 += e[0]; a1 += e[1];
    }
    if (cur >= 0) {
        atomicAdd(&pooled[(size_t)cur * HD + p2], a0);
        atomicAdd(&pooled[(size_t)cur * HD + p2 + 1], a1);
    }
}

// ---------------- classifier (fp32) ----------------
__global__ __launch_bounds__(256) void k_final(const float* __restrict__ pooled,
                                               const float* __restrict__ counts,
                                               const float* __restrict__ Wf,
                                               const float* __restrict__ bf,
                                               float* __restrict__ out) {
    int t = blockIdx.x * 256 + threadIdx.x;
    if (t >= N_GRAPHS * CLS) return;
    int g = t / CLS, c = t % CLS;
    float inv = 1.0f / fmaxf(counts[g], 1.0f);
    float s = 0.f;
    for (int k = 0; k < HD; ++k) s += pooled[(size_t)g * HD + k] * Wf[k * CLS + c];
    out[t] = s * inv + bf[c];
}

extern "C" void kernel_launch(void* const* d_in, const int* in_sizes, int n_in,
                              void* d_out, int out_size, void* d_ws, size_t ws_size,
                              hipStream_t stream) {
    const float* features = (const float*)d_in[0];
    const int*   esrc     = (const int*)d_in[1];
    const int*   edst     = (const int*)d_in[2];
    const int*   gids     = (const int*)d_in[3];
    const float* bs[3]  = {(const float*)d_in[6], (const float*)d_in[9], (const float*)d_in[12]};
    const float* Wf = (const float*)d_in[13];
    const float* bfv = (const float*)d_in[14];
    float* out = (float*)d_out;

    int* deg_i  = (int*)d_ws;            // 50000 + gcount(8), zeroed as 50064 block
    int* gcount = deg_i + 50000;
    int* rowptr = deg_i + 50064;
    int* cursor = rowptr + 50064;
    int* bsum   = cursor + 50048;
    int* eidx   = bsum + 256;
    int2* stag  = (int2*)(eidx + 800000);
    float* pooled = (float*)(stag + (size_t)NPART * PCAP);
    float* counts = pooled + N_GRAPHS * HD;
    unsigned short* C0 = (unsigned short*)(counts + 128);    // 50000*256 fp16 x3 (h|msg)
    unsigned short* C1 = C0 + (size_t)N_NODES * K2;
    unsigned short* C2 = C1 + (size_t)N_NODES * K2;
    unsigned short* Wt = C2 + (size_t)N_NODES * K2;
    unsigned char* F0 = (unsigned char*)(Wt + 3 * HD * K2);
    unsigned char* F1 = F0 + (size_t)N_NODES * HD;
    unsigned char* F2 = F1 + (size_t)N_NODES * HD;

    k_init<<<(INIT_THREADS + 255) / 256, 256, 0, stream>>>(
        features, C0, F0,
        (const float*)d_in[4], (const float*)d_in[5],
        (const float*)d_in[7], (const float*)d_in[8],
        (const float*)d_in[10], (const float*)d_in[11],
        Wt, deg_i, pooled, gids, counts);

    k_bin<<<NBIN, 256, 0, stream>>>(esrc, edst, stag, gcount);
    k_deg2<<<NPART * 64, 256, 0, stream>>>(stag, gcount, deg_i);
    k_scan_part<<<NB_SCAN, 256, 0, stream>>>(deg_i, rowptr, bsum);
    k_scan_add<<<NB_SCAN, 256, 0, stream>>>(rowptr, bsum, cursor);
    k_fill2<<<NPART * 64, 256, 0, stream>>>(stag, gcount, cursor, eidx);

    unsigned short* C[4] = {C0, C1, C2, C0};
    unsigned char* F[4] = {F0, F1, F2, F0};
    for (int l = 0; l < 3; ++l) {
        k_gather<<<(N_NODES * 64 + 255) / 256, 256, 0, stream>>>(F[l], rowptr, eidx, C[l]);
        k_sage<<<(N_NODES + 127) / 128, 256, 0, stream>>>(
            C[l], Wt + (size_t)l * HD * K2, bs[l], C[l + 1], F[l + 1], (l < 2) ? 1 : 0);
    }

    // pool reads the fp8 shadow of layer-3 output (F0)
    k_pool<<<(N_NODES + 127) / 128, 256, 0, stream>>>(F0, gids, pooled);
    k_final<<<(N_GRAPHS * CLS + 255) / 256, 256, 0, stream>>>(pooled, counts, Wf, bfv, out);
}